// Round 11
// baseline (69.598 us; speedup 1.0000x reference)
//
#include <hip/hip_runtime.h>
#include <cstdint>
#include <cstddef>

#define NS_ROWS 4096
#define NT_ROWS 4096
#define DIM 1024
#define NC 4
#define NWORK_MAX 2432
#define ACC_N 26

typedef __attribute__((ext_vector_type(4))) float f32x4;
typedef long long i64;

#define GLOBAL_AS __attribute__((address_space(1)))
#define LDS_AS __attribute__((address_space(3)))

// ---------------- ws layout ----------------
// fs (fp8, class-permuted source rows) @ 0        4,194,304 B
// ft (fp8, class-permuted target rows) @ 4194304  4,194,304 B
// p = ws + 8388608:
//   nS@0 wS@16K cS@32K nT@48K wT@64K cT@80K  (16 KB each)
//   ctrl@96K (28 ints)  acc@96K+128 (26 f)  wl@96K+512 (NWORK_MAX int4)
//   dstS@after wl  dstT@+16K
// ctrl: [0..3]cntS [4..7]cntT [16..19]baseS [20..23]baseT [24]nwork [25]doneCnt
// acc: [0]ce [1]ent [10..13]tr_t [14..17]ss_s [18..21]ss_t [22..25]ss_st

__device__ __forceinline__ int argmax4(float4 l) {
    int am = 0; float bm = l.x;
    if (l.y > bm) { bm = l.y; am = 1; }
    if (l.z > bm) { bm = l.z; am = 2; }
    if (l.w > bm) { bm = l.w; am = 3; }
    return am;
}

// Fused: deterministic counting-sort rank (wave-scan) + per-class counts/bases
// + per-row logits losses. block 0 = source, block 1 = target.
__global__ __launch_bounds__(1024)
void rank_prep(const int* __restrict__ labels, const float* __restrict__ LS,
               const float* __restrict__ LT,
               int* __restrict__ ctrl, float* __restrict__ acc,
               int* __restrict__ dstS, int* __restrict__ dstT) {
    __shared__ unsigned long long wtot[16];
    __shared__ float wred[16];
    __shared__ float cls4[NC];
    int t = threadIdx.x;
    int wid = t >> 6, lane = t & 63;
    bool isS = (blockIdx.x == 0);
    int* dst = isS ? dstS : dstT;
    const float EPSF = 1e-8f;
    const float INV_LOG2 = 1.44269504088896340736f;

    if (t < NC) cls4[t] = 0.f;

    int c4[4];
    float localScalar = 0.f;
    float localW2[NC] = {0.f, 0.f, 0.f, 0.f};
    if (isS) {
        int4 lab4 = ((const int4*)labels)[t];
        c4[0] = lab4.x; c4[1] = lab4.y; c4[2] = lab4.z; c4[3] = lab4.w;
#pragma unroll
        for (int i = 0; i < 4; ++i) {
            float4 l = ((const float4*)LS)[t * 4 + i];
            float m = fmaxf(fmaxf(l.x, l.y), fmaxf(l.z, l.w));
            float e = expf(l.x - m) + expf(l.y - m) + expf(l.z - m) + expf(l.w - m);
            float lse = m + logf(e);
            int lab = c4[i];
            float ll = (lab == 0) ? l.x : (lab == 1) ? l.y : (lab == 2) ? l.z : l.w;
            localScalar += lse - ll;
        }
    } else {
#pragma unroll
        for (int i = 0; i < 4; ++i) {
            float4 l = ((const float4*)LT)[t * 4 + i];
            int am = argmax4(l);
            c4[i] = am;
            float m = fmaxf(fmaxf(l.x, l.y), fmaxf(l.z, l.w));
            float p0 = expf(l.x - m), p1 = expf(l.y - m),
                  p2 = expf(l.z - m), p3 = expf(l.w - m);
            float s = p0 + p1 + p2 + p3;
            p0 /= s; p1 /= s; p2 /= s; p3 /= s;
            localScalar += p0 * logf(p0 + EPSF) + p1 * logf(p1 + EPSF) +
                           p2 * logf(p2 + EPSF) + p3 * logf(p3 + EPSF);
            float sumsq = p0 * p0 + p1 * p1 + p2 * p2 + p3 * p3;
            float h2 = -logf(sumsq + EPSF) * INV_LOG2;
            float w = 1.0f - h2 / (2.0f + EPSF);
            localW2[am] += w * w;
        }
    }

    unsigned long long packed = 0ULL;
#pragma unroll
    for (int i = 0; i < 4; ++i) packed += 1ULL << (c4[i] * 16);
    unsigned long long v = packed;
#pragma unroll
    for (int off = 1; off < 64; off <<= 1) {
        unsigned long long n = __shfl_up(v, off);
        if (lane >= off) v += n;
    }
    if (lane == 63) wtot[wid] = v;
    __syncthreads();
    if (t < 16) {
        unsigned long long x = wtot[t];
#pragma unroll
        for (int off = 1; off < 16; off <<= 1) {
            unsigned long long n = __shfl_up(x, off);
            if (lane >= off) x += n;
        }
        wtot[t] = x;
    }
    __syncthreads();
    unsigned long long incl = v + (wid > 0 ? wtot[wid - 1] : 0ULL);
    unsigned long long tot = wtot[15];
    unsigned long long ex = incl - packed;

    int baseC[NC]; int b = 0;
#pragma unroll
    for (int c = 0; c < NC; ++c) {
        baseC[c] = b;
        b += (int)((tot >> (c * 16)) & 0xFFFFULL);
    }
    if (t == 0) {
#pragma unroll
        for (int c = 0; c < NC; ++c) {
            ctrl[(isS ? 0 : 4) + c] = (int)((tot >> (c * 16)) & 0xFFFFULL);
            ctrl[(isS ? 16 : 20) + c] = baseC[c];
        }
    }
    int pref[NC];
#pragma unroll
    for (int c = 0; c < NC; ++c)
        pref[c] = (int)((ex >> (c * 16)) & 0xFFFFULL) + baseC[c];
#pragma unroll
    for (int i = 0; i < 4; ++i) {
        int c = c4[i];
        dst[t * 4 + i] = pref[c]++;
    }

    for (int off = 32; off; off >>= 1) localScalar += __shfl_xor(localScalar, off);
    if (lane == 0) wred[wid] = localScalar;
    if (!isS) {
#pragma unroll
        for (int c = 0; c < NC; ++c) {
            float x = localW2[c];
            for (int off = 32; off; off >>= 1) x += __shfl_xor(x, off);
            if (lane == 0 && x != 0.f) atomicAdd(&cls4[c], x);   // LDS atomic
        }
    }
    __syncthreads();
    if (t == 0) {
        float s = 0.f;
        for (int i = 0; i < 16; ++i) s += wred[i];
        acc[isS ? 0 : 1] = s;
    }
    if (!isS && t < NC) acc[10 + t] = cls4[t];
}

// fp8-convert + row norms of the QUANTIZED rows, scattered to class-contiguous
// buffers (wave per row). Block 2048 instead builds the worklist + zeroes the
// gemm accumulator slots and the done-counter (fused aux).
__global__ void scatter_aux(const float* __restrict__ FS, const float* __restrict__ FT,
                            const int* __restrict__ labels, const float* __restrict__ LT,
                            const int* __restrict__ dstS, const int* __restrict__ dstT,
                            unsigned char* __restrict__ fs, unsigned char* __restrict__ ft,
                            float* __restrict__ nS, float* __restrict__ wS, int* __restrict__ cS,
                            float* __restrict__ nT, float* __restrict__ wT, int* __restrict__ cT,
                            int* __restrict__ ctrl, int4* __restrict__ wl,
                            float* __restrict__ acc) {
    if (blockIdx.x == 2048) {   // ---- aux branch ----
        int t = threadIdx.x;
        if (t >= 12 && t < 24) acc[14 + (t - 12)] = 0.f;
        if (t == 30) ctrl[25] = 0;                       // done-counter reset
        int Ts[NC], Tt[NC];
#pragma unroll
        for (int c = 0; c < NC; ++c) {
            Ts[c] = (ctrl[c] + 127) >> 7;
            Tt[c] = (ctrl[4 + c] + 127) >> 7;
        }
        int segSize[12];
#pragma unroll
        for (int c = 0; c < NC; ++c) {
            segSize[c * 3 + 0] = Ts[c] * (Ts[c] + 1) / 2;
            segSize[c * 3 + 1] = Tt[c] * (Tt[c] + 1) / 2;
            segSize[c * 3 + 2] = Ts[c] * Tt[c];
        }
        if (t == 31) {
            int n = 0;
            for (int s = 0; s < 12; ++s) n += segSize[s];
            ctrl[24] = n;
        }
        if (t >= 12) return;
        int base = 0;
        for (int s = 0; s < t; ++s) base += segSize[s];
        int c = t / 3, kind = t % 3;
        int4* w = wl + base;
        int n = 0;
        if (kind == 0) {
            for (int tj = 0; tj < Ts[c]; ++tj)
                for (int ti = 0; ti <= tj; ++ti) w[n++] = make_int4(0, c, ti, tj);
        } else if (kind == 1) {
            for (int tj = 0; tj < Tt[c]; ++tj)
                for (int ti = 0; ti <= tj; ++ti) w[n++] = make_int4(1, c, ti, tj);
        } else {
            for (int ti = 0; ti < Ts[c]; ++ti)
                for (int tj = 0; tj < Tt[c]; ++tj) w[n++] = make_int4(2, c, ti, tj);
        }
        return;
    }

    int row = blockIdx.x * 4 + (threadIdx.x >> 6);
    int lane = threadIdx.x & 63;
    bool isS = row < NS_ROWS;
    int r = isS ? row : row - NS_ROWS;
    int dst = isS ? dstS[r] : dstT[r];

    const float* src = (isS ? FS : FT) + (size_t)r * DIM;
    float4 v0 = ((const float4*)src)[lane * 4 + 0];
    float4 v1 = ((const float4*)src)[lane * 4 + 1];
    float4 v2 = ((const float4*)src)[lane * 4 + 2];
    float4 v3 = ((const float4*)src)[lane * 4 + 3];
    int w0 = 0, w1 = 0, w2 = 0, w3 = 0;
    w0 = __builtin_amdgcn_cvt_pk_fp8_f32(v0.x, v0.y, w0, false);
    w0 = __builtin_amdgcn_cvt_pk_fp8_f32(v0.z, v0.w, w0, true);
    w1 = __builtin_amdgcn_cvt_pk_fp8_f32(v1.x, v1.y, w1, false);
    w1 = __builtin_amdgcn_cvt_pk_fp8_f32(v1.z, v1.w, w1, true);
    w2 = __builtin_amdgcn_cvt_pk_fp8_f32(v2.x, v2.y, w2, false);
    w2 = __builtin_amdgcn_cvt_pk_fp8_f32(v2.z, v2.w, w2, true);
    w3 = __builtin_amdgcn_cvt_pk_fp8_f32(v3.x, v3.y, w3, false);
    w3 = __builtin_amdgcn_cvt_pk_fp8_f32(v3.z, v3.w, w3, true);

    float ssum = 0.f;
#define ACCQ(wv)                                                       \
    do {                                                               \
        float q0 = __builtin_amdgcn_cvt_f32_fp8((wv), 0);              \
        float q1 = __builtin_amdgcn_cvt_f32_fp8((wv), 1);              \
        float q2 = __builtin_amdgcn_cvt_f32_fp8((wv), 2);              \
        float q3 = __builtin_amdgcn_cvt_f32_fp8((wv), 3);              \
        ssum += q0 * q0 + q1 * q1 + q2 * q2 + q3 * q3;                 \
    } while (0)
    ACCQ(w0); ACCQ(w1); ACCQ(w2); ACCQ(w3);
#undef ACCQ

    unsigned char* fdst = (isS ? fs : ft) + (size_t)dst * DIM;
    *(uint4*)(fdst + lane * 16) = make_uint4((unsigned)w0, (unsigned)w1,
                                             (unsigned)w2, (unsigned)w3);

    for (int off = 32; off; off >>= 1) ssum += __shfl_xor(ssum, off);

    if (lane == 0) {
        if (isS) {
            nS[dst] = ssum; wS[dst] = 1.0f; cS[dst] = labels[r];
        } else {
            float4 l = ((const float4*)LT)[r];
            int am = argmax4(l);
            float m = fmaxf(fmaxf(l.x, l.y), fmaxf(l.z, l.w));
            float p0 = expf(l.x - m), p1 = expf(l.y - m),
                  p2 = expf(l.z - m), p3 = expf(l.w - m);
            float s = p0 + p1 + p2 + p3;
            float sumsq = (p0 * p0 + p1 * p1 + p2 * p2 + p3 * p3) / (s * s);
            const float INV_LOG2 = 1.44269504088896340736f;
            float h2 = -logf(sumsq + 1e-8f) * INV_LOG2;
            float w = 1.0f - h2 / (2.0f + 1e-8f);
            nT[dst] = ssum; wT[dst] = w * w; cT[dst] = am;
        }
    }
}

// Fused fp8 GEMM (A@B^T) + RBF + weighted reduction, class-partitioned tiles.
// 128x128 tile, 4 waves, BK=64, R10's both-sides 16B-chunk XOR swizzle.
// 3-buffer counted-vmcnt pipeline (T4): per K-step = vmcnt(4) -> s_barrier ->
// STAGE(k+2) -> COMPUTE(k). vmcnt never drains to 0 in the main loop; the
// single barrier certifies (a) everyone's tile-k loads landed (each wave did
// its own vmcnt first) and (b) everyone finished computing k-1 before its
// buffer is overwritten. Last block runs finalize (device-atomic handshake).
__global__ __launch_bounds__(256, 3)
void gemm_reduce(const unsigned char* __restrict__ fs, const unsigned char* __restrict__ ft,
                 const float* __restrict__ nS, const float* __restrict__ wS, const int* __restrict__ cS,
                 const float* __restrict__ nT, const float* __restrict__ wT, const int* __restrict__ cT,
                 int* __restrict__ ctrl, const int4* __restrict__ wl,
                 float* __restrict__ acc, float* __restrict__ out) {
    __shared__ unsigned char As[3][128 * 64];
    __shared__ unsigned char Bs[3][128 * 64];
    __shared__ float sred;

    int nwork = ctrl[24];
    int chunk = (nwork + 7) >> 3;
    int sub = blockIdx.x >> 3, xcd = blockIdx.x & 7;
    if (sub >= chunk) return;
    int widx = xcd * chunk + sub;
    if (widx >= nwork) return;
    int4 it = wl[widx];
    int kind = it.x, cls = it.y, ti = it.z, tj = it.w;

    const unsigned char *A, *B;
    const float *nA, *nB, *wA, *wB;
    const int *cA, *cB;
    int baseA, baseB;
    if (kind == 0)      { A = fs; B = fs; nA = nS; nB = nS; wA = wS; wB = wS; cA = cS; cB = cS;
                          baseA = ctrl[16 + cls]; baseB = baseA; }
    else if (kind == 1) { A = ft; B = ft; nA = nT; nB = nT; wA = wT; wB = wT; cA = cT; cB = cT;
                          baseA = ctrl[20 + cls]; baseB = baseA; }
    else                { A = fs; B = ft; nA = nS; nB = nT; wA = wS; cA = cS; cB = cT;
                          wB = wS;   // ss_st is mask-only on both sides
                          baseA = ctrl[16 + cls]; baseB = ctrl[20 + cls]; }
    float* outp = acc + 14 + kind * 4 + cls;
    float factor = (kind != 2 && ti != tj) ? 2.0f : 1.0f;

    int tid = threadIdx.x;
    int lane = tid & 63;
    int wid = tid >> 6;
    int wr = wid >> 1, wc = wid & 1;

    int rowA0 = baseA + ti * 128;
    int rowB0 = baseB + tj * 128;

    int srow = tid >> 2;                              // 0..63
    int sb = (((tid & 3) ^ ((tid >> 3) & 3))) * 16;   // inverse-swizzled src chunk

    const unsigned char* pa0 = A + (size_t)min(rowA0 + srow,      4095) * DIM + sb;
    const unsigned char* pa1 = A + (size_t)min(rowA0 + srow + 64, 4095) * DIM + sb;
    const unsigned char* pb0 = B + (size_t)min(rowB0 + srow,      4095) * DIM + sb;
    const unsigned char* pb1 = B + (size_t)min(rowB0 + srow + 64, 4095) * DIM + sb;

    f32x4 accf[4][4];
#pragma unroll
    for (int m = 0; m < 4; ++m)
#pragma unroll
        for (int n = 0; n < 4; ++n) accf[m][n] = (f32x4)(0.f);

    int lr = lane & 15;
    int lk = (lane >> 4) * 8;
    int sw = (lr >> 1) & 3;             // per-lane swizzle key

#define STAGE(buf, kt)                                                            \
    do {                                                                          \
        int k0_ = (kt) * 64;                                                      \
        __builtin_amdgcn_global_load_lds((const GLOBAL_AS void*)(pa0 + k0_),      \
            (LDS_AS void*)(As[buf] + tid * 16), 16, 0, 0);                        \
        __builtin_amdgcn_global_load_lds((const GLOBAL_AS void*)(pa1 + k0_),      \
            (LDS_AS void*)(As[buf] + 4096 + tid * 16), 16, 0, 0);                 \
        __builtin_amdgcn_global_load_lds((const GLOBAL_AS void*)(pb0 + k0_),      \
            (LDS_AS void*)(Bs[buf] + tid * 16), 16, 0, 0);                        \
        __builtin_amdgcn_global_load_lds((const GLOBAL_AS void*)(pb1 + k0_),      \
            (LDS_AS void*)(Bs[buf] + 4096 + tid * 16), 16, 0, 0);                 \
    } while (0)

#define COMPUTE_HALF(buf, kk)                                                     \
    do {                                                                          \
        int b_ = (kk) + lk;                                                       \
        int bs_ = ((((b_) >> 4) ^ sw) << 4) | ((b_) & 15);                        \
        i64 af[4], bfr[4];                                                        \
        _Pragma("unroll")                                                         \
        for (int f = 0; f < 4; ++f)                                               \
            af[f] = *(const i64*)(As[buf] + (wr * 64 + f * 16 + lr) * 64 + bs_);  \
        _Pragma("unroll")                                                         \
        for (int f = 0; f < 4; ++f)                                               \
            bfr[f] = *(const i64*)(Bs[buf] + (wc * 64 + f * 16 + lr) * 64 + bs_); \
        _Pragma("unroll")                                                         \
        for (int m = 0; m < 4; ++m)                                               \
            _Pragma("unroll")                                                     \
            for (int n = 0; n < 4; ++n)                                           \
                accf[m][n] = __builtin_amdgcn_mfma_f32_16x16x32_fp8_fp8(          \
                    af[m], bfr[n], accf[m][n], 0, 0, 0);                          \
    } while (0)

    // prologue: 2 tiles in flight (8 loads)
    STAGE(0, 0);
    STAGE(1, 1);

    int bcur = 0;
    for (int kt = 0; kt < DIM / 64 - 2; ++kt) {       // kt = 0..13
        asm volatile("s_waitcnt vmcnt(4)" ::: "memory");   // tile kt's 4 loads done
        __builtin_amdgcn_s_barrier();
        int bst = bcur + 2; if (bst >= 3) bst -= 3;
        STAGE(bst, kt + 2);                            // overwrites buf[(kt-1)%3]
        COMPUTE_HALF(bcur, 0);
        COMPUTE_HALF(bcur, 32);
        ++bcur; if (bcur == 3) bcur = 0;
    }
    // kt = 14: tiles 14,15 outstanding (8 loads) -> wait tile 14
    asm volatile("s_waitcnt vmcnt(4)" ::: "memory");
    __builtin_amdgcn_s_barrier();
    COMPUTE_HALF(bcur, 0);
    COMPUTE_HALF(bcur, 32);
    ++bcur; if (bcur == 3) bcur = 0;
    // kt = 15: drain
    asm volatile("s_waitcnt vmcnt(0)" ::: "memory");
    __builtin_amdgcn_s_barrier();
    COMPUTE_HALF(bcur, 0);
    COMPUTE_HALF(bcur, 32);

    // ---- fused epilogue: d2 -> K^2 -> weighted accumulate ----
    int rowBase = rowA0 + wr * 64;
    int colBase = rowB0 + wc * 64;

    float cn[4], cw[4];
#pragma unroll
    for (int f = 0; f < 4; ++f) {
        int gj = colBase + f * 16 + lr;
        int gjc = min(gj, 4095);
        cn[f] = nB[gjc];
        cw[f] = (gj < 4096 && cB[gjc] == cls) ? wB[gjc] : 0.0f;
    }

    const float NEGF = (-2.0f / (2.0f * 32.0f * 32.0f + 1e-8f)) * 1.44269504088896340736f;
    float lacc = 0.f;

#pragma unroll
    for (int m = 0; m < 4; ++m) {
#pragma unroll
        for (int j = 0; j < 4; ++j) {
            int gi = rowBase + m * 16 + (lane >> 4) * 4 + j;
            int gic = min(gi, 4095);
            float rn = nA[gic];
            float rw = (gi < 4096 && cA[gic] == cls) ? wA[gic] : 0.0f;
#pragma unroll
            for (int n = 0; n < 4; ++n) {
                float dot = accf[m][n][j];
                float d2 = rn + cn[n] - 2.0f * dot;
                d2 = fmaxf(d2, 0.0f);
                float k2 = exp2f(d2 * NEGF);        // = K^2
                lacc += k2 * rw * cw[n];
            }
        }
    }

    if (tid == 0) sred = 0.f;
    __syncthreads();
    for (int off = 32; off; off >>= 1) lacc += __shfl_xor(lacc, off);
    if (lane == 0) atomicAdd(&sred, lacc);
    __syncthreads();

    if (tid == 0) {
        atomicAdd(outp, factor * sred);
        __threadfence();                               // release: acc RMW before counter RMW
        int done = atomicAdd(&ctrl[25], 1);
        if (done == nwork - 1) {                       // last block: finalize
            __threadfence();                           // acquire
            const double EPS = 1e-8;
            const double LOG2 = 0.6931471805599453;
            double av[12];
            for (int i = 0; i < 12; ++i)
                av[i] = (double)atomicAdd(&acc[14 + i], 0.0f);   // L2 RMW read
            double loss_cls = (double)acc[0] / NS_ROWS;
            double loss_ent = -(double)acc[1] / NT_ROWS;
            double creda_sum = 0.0, n_valid = 0.0;
            for (int c = 0; c < NC; ++c) {
                int nsc_i = ctrl[c], ntc_i = ctrl[4 + c];
                double trt = acc[10 + c];
                double sss = av[c], sst = av[4 + c], ssst = av[8 + c];
                double trs = (double)nsc_i;
                double info_s = sss / ((trs + EPS) * (trs + EPS));
                double h_s = -log(info_s + EPS) / LOG2;
                double info_t = sst / ((trt + EPS) * (trt + EPS));
                double h_t = -log(info_t + EPS) / LOG2;
                double trm = trs + trt;
                double ssm = sss + 2.0 * ssst + sst;
                double info_m = ssm / ((trm + EPS) * (trm + EPS));
                double h_m = -log(info_m + EPS) / LOG2;
                double pc = h_m - 0.5 * (h_s + h_t);
                if (nsc_i >= 2 && ntc_i >= 2) { creda_sum += pc; n_valid += 1.0; }
            }
            double creda = (n_valid > 0.0) ? creda_sum / n_valid : 0.0;
            out[0] = (float)(loss_cls + 1.0 * creda + 0.1 * loss_ent);
        }
    }
#undef STAGE
#undef COMPUTE_HALF
}

extern "C" void kernel_launch(void* const* d_in, const int* in_sizes, int n_in,
                              void* d_out, int out_size, void* d_ws, size_t ws_size,
                              hipStream_t stream) {
    const float* FS = (const float*)d_in[0];
    const float* LS = (const float*)d_in[1];
    const float* FT = (const float*)d_in[2];
    const float* LT = (const float*)d_in[3];
    const int* LAB = (const int*)d_in[4];

    char* ws = (char*)d_ws;
    unsigned char* fs = (unsigned char*)(ws);                 // 4 MB
    unsigned char* ft = (unsigned char*)(ws + 4194304);       // 4 MB
    char* p = ws + 8388608;
    float* nS  = (float*)(p);
    float* wS  = (float*)(p + 16384);
    int*   cS  = (int*)  (p + 32768);
    float* nT  = (float*)(p + 49152);
    float* wT  = (float*)(p + 65536);
    int*   cT  = (int*)  (p + 81920);
    int*   ctrl = (int*)  (p + 98304);        // 28 ints
    float* acc  = (float*)(p + 98304 + 128);  // 26 floats
    int4*  wl   = (int4*) (p + 98304 + 512);  // NWORK_MAX x 16 B
    int*   dstS = (int*)  (p + 98304 + 512 + NWORK_MAX * 16);
    int*   dstT = dstS + NS_ROWS;

    rank_prep<<<2, 1024, 0, stream>>>(LAB, LS, LT, ctrl, acc, dstS, dstT);
    scatter_aux<<<2049, 256, 0, stream>>>(FS, FT, LAB, LT, dstS, dstT, fs, ft,
                                          nS, wS, cS, nT, wT, cT, ctrl, wl, acc);
    gemm_reduce<<<NWORK_MAX, 256, 0, stream>>>(fs, ft, nS, wS, cS, nT, wT, cT,
                                               ctrl, wl, acc, (float*)d_out);
}

// Round 12
// 67.809 us; speedup vs baseline: 1.0264x; 1.0264x over previous
//
#include <hip/hip_runtime.h>
#include <cstdint>
#include <cstddef>

#define NS_ROWS 4096
#define NT_ROWS 4096
#define DIM 1024
#define NC 4
#define NWORK_MAX 2432
#define ACC_N 26

typedef __attribute__((ext_vector_type(4))) float f32x4;
typedef long long i64;

#define GLOBAL_AS __attribute__((address_space(1)))
#define LDS_AS __attribute__((address_space(3)))

// ---------------- ws layout ----------------
// fs (fp8, class-permuted source rows) @ 0        4,194,304 B
// ft (fp8, class-permuted target rows) @ 4194304  4,194,304 B
// p = ws + 8388608:
//   nS@0 wS@16K cS@32K nT@48K wT@64K cT@80K  (16 KB each)
//   ctrl@96K (28 ints)  acc@96K+128 (26 f)  wl@96K+512 (NWORK_MAX int4)
//   dstS@after wl  dstT@+16K
// ctrl: [0..3]cntS [4..7]cntT [16..19]baseS [20..23]baseT [24]nwork [25]doneCnt
// acc: [0]ce [1]ent [10..13]tr_t [14..17]ss_s [18..21]ss_t [22..25]ss_st

__device__ __forceinline__ int argmax4(float4 l) {
    int am = 0; float bm = l.x;
    if (l.y > bm) { bm = l.y; am = 1; }
    if (l.z > bm) { bm = l.z; am = 2; }
    if (l.w > bm) { bm = l.w; am = 3; }
    return am;
}

// Fused: deterministic counting-sort rank (wave-scan) + per-class counts/bases
// + per-row logits losses. block 0 = source, block 1 = target.
__global__ __launch_bounds__(1024)
void rank_prep(const int* __restrict__ labels, const float* __restrict__ LS,
               const float* __restrict__ LT,
               int* __restrict__ ctrl, float* __restrict__ acc,
               int* __restrict__ dstS, int* __restrict__ dstT) {
    __shared__ unsigned long long wtot[16];
    __shared__ float wred[16];
    __shared__ float cls4[NC];
    int t = threadIdx.x;
    int wid = t >> 6, lane = t & 63;
    bool isS = (blockIdx.x == 0);
    int* dst = isS ? dstS : dstT;
    const float EPSF = 1e-8f;
    const float INV_LOG2 = 1.44269504088896340736f;

    if (t < NC) cls4[t] = 0.f;

    int c4[4];
    float localScalar = 0.f;
    float localW2[NC] = {0.f, 0.f, 0.f, 0.f};
    if (isS) {
        int4 lab4 = ((const int4*)labels)[t];
        c4[0] = lab4.x; c4[1] = lab4.y; c4[2] = lab4.z; c4[3] = lab4.w;
#pragma unroll
        for (int i = 0; i < 4; ++i) {
            float4 l = ((const float4*)LS)[t * 4 + i];
            float m = fmaxf(fmaxf(l.x, l.y), fmaxf(l.z, l.w));
            float e = expf(l.x - m) + expf(l.y - m) + expf(l.z - m) + expf(l.w - m);
            float lse = m + logf(e);
            int lab = c4[i];
            float ll = (lab == 0) ? l.x : (lab == 1) ? l.y : (lab == 2) ? l.z : l.w;
            localScalar += lse - ll;
        }
    } else {
#pragma unroll
        for (int i = 0; i < 4; ++i) {
            float4 l = ((const float4*)LT)[t * 4 + i];
            int am = argmax4(l);
            c4[i] = am;
            float m = fmaxf(fmaxf(l.x, l.y), fmaxf(l.z, l.w));
            float p0 = expf(l.x - m), p1 = expf(l.y - m),
                  p2 = expf(l.z - m), p3 = expf(l.w - m);
            float s = p0 + p1 + p2 + p3;
            p0 /= s; p1 /= s; p2 /= s; p3 /= s;
            localScalar += p0 * logf(p0 + EPSF) + p1 * logf(p1 + EPSF) +
                           p2 * logf(p2 + EPSF) + p3 * logf(p3 + EPSF);
            float sumsq = p0 * p0 + p1 * p1 + p2 * p2 + p3 * p3;
            float h2 = -logf(sumsq + EPSF) * INV_LOG2;
            float w = 1.0f - h2 / (2.0f + EPSF);
            localW2[am] += w * w;
        }
    }

    unsigned long long packed = 0ULL;
#pragma unroll
    for (int i = 0; i < 4; ++i) packed += 1ULL << (c4[i] * 16);
    unsigned long long v = packed;
#pragma unroll
    for (int off = 1; off < 64; off <<= 1) {
        unsigned long long n = __shfl_up(v, off);
        if (lane >= off) v += n;
    }
    if (lane == 63) wtot[wid] = v;
    __syncthreads();
    if (t < 16) {
        unsigned long long x = wtot[t];
#pragma unroll
        for (int off = 1; off < 16; off <<= 1) {
            unsigned long long n = __shfl_up(x, off);
            if (lane >= off) x += n;
        }
        wtot[t] = x;
    }
    __syncthreads();
    unsigned long long incl = v + (wid > 0 ? wtot[wid - 1] : 0ULL);
    unsigned long long tot = wtot[15];
    unsigned long long ex = incl - packed;

    int baseC[NC]; int b = 0;
#pragma unroll
    for (int c = 0; c < NC; ++c) {
        baseC[c] = b;
        b += (int)((tot >> (c * 16)) & 0xFFFFULL);
    }
    if (t == 0) {
#pragma unroll
        for (int c = 0; c < NC; ++c) {
            ctrl[(isS ? 0 : 4) + c] = (int)((tot >> (c * 16)) & 0xFFFFULL);
            ctrl[(isS ? 16 : 20) + c] = baseC[c];
        }
    }
    int pref[NC];
#pragma unroll
    for (int c = 0; c < NC; ++c)
        pref[c] = (int)((ex >> (c * 16)) & 0xFFFFULL) + baseC[c];
#pragma unroll
    for (int i = 0; i < 4; ++i) {
        int c = c4[i];
        dst[t * 4 + i] = pref[c]++;
    }

    for (int off = 32; off; off >>= 1) localScalar += __shfl_xor(localScalar, off);
    if (lane == 0) wred[wid] = localScalar;
    if (!isS) {
#pragma unroll
        for (int c = 0; c < NC; ++c) {
            float x = localW2[c];
            for (int off = 32; off; off >>= 1) x += __shfl_xor(x, off);
            if (lane == 0 && x != 0.f) atomicAdd(&cls4[c], x);   // LDS atomic
        }
    }
    __syncthreads();
    if (t == 0) {
        float s = 0.f;
        for (int i = 0; i < 16; ++i) s += wred[i];
        acc[isS ? 0 : 1] = s;
    }
    if (!isS && t < NC) acc[10 + t] = cls4[t];
}

// fp8-convert + row norms of the QUANTIZED rows, scattered to class-contiguous
// buffers (wave per row). Block 2048 instead builds the worklist + zeroes the
// gemm accumulator slots and the done-counter (fused aux).
__global__ void scatter_aux(const float* __restrict__ FS, const float* __restrict__ FT,
                            const int* __restrict__ labels, const float* __restrict__ LT,
                            const int* __restrict__ dstS, const int* __restrict__ dstT,
                            unsigned char* __restrict__ fs, unsigned char* __restrict__ ft,
                            float* __restrict__ nS, float* __restrict__ wS, int* __restrict__ cS,
                            float* __restrict__ nT, float* __restrict__ wT, int* __restrict__ cT,
                            int* __restrict__ ctrl, int4* __restrict__ wl,
                            float* __restrict__ acc) {
    if (blockIdx.x == 2048) {   // ---- aux branch ----
        int t = threadIdx.x;
        if (t >= 12 && t < 24) acc[14 + (t - 12)] = 0.f;
        if (t == 30) ctrl[25] = 0;                       // done-counter reset
        int Ts[NC], Tt[NC];
#pragma unroll
        for (int c = 0; c < NC; ++c) {
            Ts[c] = (ctrl[c] + 127) >> 7;
            Tt[c] = (ctrl[4 + c] + 127) >> 7;
        }
        int segSize[12];
#pragma unroll
        for (int c = 0; c < NC; ++c) {
            segSize[c * 3 + 0] = Ts[c] * (Ts[c] + 1) / 2;
            segSize[c * 3 + 1] = Tt[c] * (Tt[c] + 1) / 2;
            segSize[c * 3 + 2] = Ts[c] * Tt[c];
        }
        if (t == 31) {
            int n = 0;
            for (int s = 0; s < 12; ++s) n += segSize[s];
            ctrl[24] = n;
        }
        if (t >= 12) return;
        int base = 0;
        for (int s = 0; s < t; ++s) base += segSize[s];
        int c = t / 3, kind = t % 3;
        int4* w = wl + base;
        int n = 0;
        if (kind == 0) {
            for (int tj = 0; tj < Ts[c]; ++tj)
                for (int ti = 0; ti <= tj; ++ti) w[n++] = make_int4(0, c, ti, tj);
        } else if (kind == 1) {
            for (int tj = 0; tj < Tt[c]; ++tj)
                for (int ti = 0; ti <= tj; ++ti) w[n++] = make_int4(1, c, ti, tj);
        } else {
            for (int ti = 0; ti < Ts[c]; ++ti)
                for (int tj = 0; tj < Tt[c]; ++tj) w[n++] = make_int4(2, c, ti, tj);
        }
        return;
    }

    int row = blockIdx.x * 4 + (threadIdx.x >> 6);
    int lane = threadIdx.x & 63;
    bool isS = row < NS_ROWS;
    int r = isS ? row : row - NS_ROWS;
    int dst = isS ? dstS[r] : dstT[r];

    const float* src = (isS ? FS : FT) + (size_t)r * DIM;
    float4 v0 = ((const float4*)src)[lane * 4 + 0];
    float4 v1 = ((const float4*)src)[lane * 4 + 1];
    float4 v2 = ((const float4*)src)[lane * 4 + 2];
    float4 v3 = ((const float4*)src)[lane * 4 + 3];
    int w0 = 0, w1 = 0, w2 = 0, w3 = 0;
    w0 = __builtin_amdgcn_cvt_pk_fp8_f32(v0.x, v0.y, w0, false);
    w0 = __builtin_amdgcn_cvt_pk_fp8_f32(v0.z, v0.w, w0, true);
    w1 = __builtin_amdgcn_cvt_pk_fp8_f32(v1.x, v1.y, w1, false);
    w1 = __builtin_amdgcn_cvt_pk_fp8_f32(v1.z, v1.w, w1, true);
    w2 = __builtin_amdgcn_cvt_pk_fp8_f32(v2.x, v2.y, w2, false);
    w2 = __builtin_amdgcn_cvt_pk_fp8_f32(v2.z, v2.w, w2, true);
    w3 = __builtin_amdgcn_cvt_pk_fp8_f32(v3.x, v3.y, w3, false);
    w3 = __builtin_amdgcn_cvt_pk_fp8_f32(v3.z, v3.w, w3, true);

    float ssum = 0.f;
#define ACCQ(wv)                                                       \
    do {                                                               \
        float q0 = __builtin_amdgcn_cvt_f32_fp8((wv), 0);              \
        float q1 = __builtin_amdgcn_cvt_f32_fp8((wv), 1);              \
        float q2 = __builtin_amdgcn_cvt_f32_fp8((wv), 2);              \
        float q3 = __builtin_amdgcn_cvt_f32_fp8((wv), 3);              \
        ssum += q0 * q0 + q1 * q1 + q2 * q2 + q3 * q3;                 \
    } while (0)
    ACCQ(w0); ACCQ(w1); ACCQ(w2); ACCQ(w3);
#undef ACCQ

    unsigned char* fdst = (isS ? fs : ft) + (size_t)dst * DIM;
    *(uint4*)(fdst + lane * 16) = make_uint4((unsigned)w0, (unsigned)w1,
                                             (unsigned)w2, (unsigned)w3);

    for (int off = 32; off; off >>= 1) ssum += __shfl_xor(ssum, off);

    if (lane == 0) {
        if (isS) {
            nS[dst] = ssum; wS[dst] = 1.0f; cS[dst] = labels[r];
        } else {
            float4 l = ((const float4*)LT)[r];
            int am = argmax4(l);
            float m = fmaxf(fmaxf(l.x, l.y), fmaxf(l.z, l.w));
            float p0 = expf(l.x - m), p1 = expf(l.y - m),
                  p2 = expf(l.z - m), p3 = expf(l.w - m);
            float s = p0 + p1 + p2 + p3;
            float sumsq = (p0 * p0 + p1 * p1 + p2 * p2 + p3 * p3) / (s * s);
            const float INV_LOG2 = 1.44269504088896340736f;
            float h2 = -logf(sumsq + 1e-8f) * INV_LOG2;
            float w = 1.0f - h2 / (2.0f + 1e-8f);
            nT[dst] = ssum; wT[dst] = w * w; cT[dst] = am;
        }
    }
}

// Fused fp8 GEMM (A@B^T) + RBF + weighted reduction, class-partitioned tiles.
// REVERTED to the R10-verified 2-phase / 2-buffer pipeline (32.6us): T4's
// counted-vmcnt 3-buffer variant regressed (48.8us) — occupancy 4->3 blocks/CU
// killed the inter-block overlap that does the latency hiding here (m114),
// and the coarse 1-phase K-step can't exploit pipeline depth (m232 regime gate).
// 128x128 tile, 4 waves, BK=64, both-sides 16B-chunk XOR swizzle.
// Last block runs finalize (device-atomic handshake).
__global__ __launch_bounds__(256, 4)
void gemm_reduce(const unsigned char* __restrict__ fs, const unsigned char* __restrict__ ft,
                 const float* __restrict__ nS, const float* __restrict__ wS, const int* __restrict__ cS,
                 const float* __restrict__ nT, const float* __restrict__ wT, const int* __restrict__ cT,
                 int* __restrict__ ctrl, const int4* __restrict__ wl,
                 float* __restrict__ acc, float* __restrict__ out) {
    __shared__ unsigned char As[2][128 * 64];
    __shared__ unsigned char Bs[2][128 * 64];
    __shared__ float sred;

    int nwork = ctrl[24];
    int chunk = (nwork + 7) >> 3;
    int sub = blockIdx.x >> 3, xcd = blockIdx.x & 7;
    if (sub >= chunk) return;
    int widx = xcd * chunk + sub;
    if (widx >= nwork) return;
    int4 it = wl[widx];
    int kind = it.x, cls = it.y, ti = it.z, tj = it.w;

    const unsigned char *A, *B;
    const float *nA, *nB, *wA, *wB;
    const int *cA, *cB;
    int baseA, baseB;
    if (kind == 0)      { A = fs; B = fs; nA = nS; nB = nS; wA = wS; wB = wS; cA = cS; cB = cS;
                          baseA = ctrl[16 + cls]; baseB = baseA; }
    else if (kind == 1) { A = ft; B = ft; nA = nT; nB = nT; wA = wT; wB = wT; cA = cT; cB = cT;
                          baseA = ctrl[20 + cls]; baseB = baseA; }
    else                { A = fs; B = ft; nA = nS; nB = nT; wA = wS; cA = cS; cB = cT;
                          wB = wS;   // ss_st is mask-only on both sides
                          baseA = ctrl[16 + cls]; baseB = ctrl[20 + cls]; }
    float* outp = acc + 14 + kind * 4 + cls;
    float factor = (kind != 2 && ti != tj) ? 2.0f : 1.0f;

    int tid = threadIdx.x;
    int lane = tid & 63;
    int wid = tid >> 6;
    int wr = wid >> 1, wc = wid & 1;

    int rowA0 = baseA + ti * 128;
    int rowB0 = baseB + tj * 128;

    int srow = tid >> 2;                              // 0..63
    int sb = (((tid & 3) ^ ((tid >> 3) & 3))) * 16;   // inverse-swizzled src chunk

    const unsigned char* pa0 = A + (size_t)min(rowA0 + srow,      4095) * DIM + sb;
    const unsigned char* pa1 = A + (size_t)min(rowA0 + srow + 64, 4095) * DIM + sb;
    const unsigned char* pb0 = B + (size_t)min(rowB0 + srow,      4095) * DIM + sb;
    const unsigned char* pb1 = B + (size_t)min(rowB0 + srow + 64, 4095) * DIM + sb;

    f32x4 accf[4][4];
#pragma unroll
    for (int m = 0; m < 4; ++m)
#pragma unroll
        for (int n = 0; n < 4; ++n) accf[m][n] = (f32x4)(0.f);

    int lr = lane & 15;
    int lk = (lane >> 4) * 8;
    int sw = (lr >> 1) & 3;             // per-lane swizzle key

#define STAGE(buf, kt)                                                            \
    do {                                                                          \
        int k0_ = (kt) * 64;                                                      \
        __builtin_amdgcn_global_load_lds((const GLOBAL_AS void*)(pa0 + k0_),      \
            (LDS_AS void*)(As[buf] + tid * 16), 16, 0, 0);                        \
        __builtin_amdgcn_global_load_lds((const GLOBAL_AS void*)(pa1 + k0_),      \
            (LDS_AS void*)(As[buf] + 4096 + tid * 16), 16, 0, 0);                 \
        __builtin_amdgcn_global_load_lds((const GLOBAL_AS void*)(pb0 + k0_),      \
            (LDS_AS void*)(Bs[buf] + tid * 16), 16, 0, 0);                        \
        __builtin_amdgcn_global_load_lds((const GLOBAL_AS void*)(pb1 + k0_),      \
            (LDS_AS void*)(Bs[buf] + 4096 + tid * 16), 16, 0, 0);                 \
    } while (0)

#define COMPUTE_HALF(buf, kk)                                                     \
    do {                                                                          \
        int b_ = (kk) + lk;                                                       \
        int bs_ = ((((b_) >> 4) ^ sw) << 4) | ((b_) & 15);                        \
        i64 af[4], bfr[4];                                                        \
        _Pragma("unroll")                                                         \
        for (int f = 0; f < 4; ++f)                                               \
            af[f] = *(const i64*)(As[buf] + (wr * 64 + f * 16 + lr) * 64 + bs_);  \
        _Pragma("unroll")                                                         \
        for (int f = 0; f < 4; ++f)                                               \
            bfr[f] = *(const i64*)(Bs[buf] + (wc * 64 + f * 16 + lr) * 64 + bs_); \
        _Pragma("unroll")                                                         \
        for (int m = 0; m < 4; ++m)                                               \
            _Pragma("unroll")                                                     \
            for (int n = 0; n < 4; ++n)                                           \
                accf[m][n] = __builtin_amdgcn_mfma_f32_16x16x32_fp8_fp8(          \
                    af[m], bfr[n], accf[m][n], 0, 0, 0);                          \
    } while (0)

    STAGE(0, 0);
    asm volatile("s_waitcnt vmcnt(0)");
    __syncthreads();

    int cur = 0;
    for (int kt = 0; kt < DIM / 64 - 1; ++kt) {
        STAGE(cur ^ 1, kt + 1);     // next tile's loads fly during compute
        COMPUTE_HALF(cur, 0);
        COMPUTE_HALF(cur, 32);
        __syncthreads();            // drains vmcnt(0)+lgkmcnt(0); next buf ready
        cur ^= 1;
    }
    COMPUTE_HALF(cur, 0);
    COMPUTE_HALF(cur, 32);

    // ---- fused epilogue: d2 -> K^2 -> weighted accumulate ----
    int rowBase = rowA0 + wr * 64;
    int colBase = rowB0 + wc * 64;

    float cn[4], cw[4];
#pragma unroll
    for (int f = 0; f < 4; ++f) {
        int gj = colBase + f * 16 + lr;
        int gjc = min(gj, 4095);
        cn[f] = nB[gjc];
        cw[f] = (gj < 4096 && cB[gjc] == cls) ? wB[gjc] : 0.0f;
    }

    const float NEGF = (-2.0f / (2.0f * 32.0f * 32.0f + 1e-8f)) * 1.44269504088896340736f;
    float lacc = 0.f;

#pragma unroll
    for (int m = 0; m < 4; ++m) {
#pragma unroll
        for (int j = 0; j < 4; ++j) {
            int gi = rowBase + m * 16 + (lane >> 4) * 4 + j;
            int gic = min(gi, 4095);
            float rn = nA[gic];
            float rw = (gi < 4096 && cA[gic] == cls) ? wA[gic] : 0.0f;
#pragma unroll
            for (int n = 0; n < 4; ++n) {
                float dot = accf[m][n][j];
                float d2 = rn + cn[n] - 2.0f * dot;
                d2 = fmaxf(d2, 0.0f);
                float k2 = exp2f(d2 * NEGF);        // = K^2
                lacc += k2 * rw * cw[n];
            }
        }
    }

    if (tid == 0) sred = 0.f;
    __syncthreads();
    for (int off = 32; off; off >>= 1) lacc += __shfl_xor(lacc, off);
    if (lane == 0) atomicAdd(&sred, lacc);
    __syncthreads();

    if (tid == 0) {
        atomicAdd(outp, factor * sred);
        __threadfence();                               // release: acc RMW before counter RMW
        int done = atomicAdd(&ctrl[25], 1);
        if (done == nwork - 1) {                       // last block: finalize
            __threadfence();                           // acquire
            const double EPS = 1e-8;
            const double LOG2 = 0.6931471805599453;
            double av[12];
            for (int i = 0; i < 12; ++i)
                av[i] = (double)atomicAdd(&acc[14 + i], 0.0f);   // L2 RMW read
            double loss_cls = (double)acc[0] / NS_ROWS;
            double loss_ent = -(double)acc[1] / NT_ROWS;
            double creda_sum = 0.0, n_valid = 0.0;
            for (int c = 0; c < NC; ++c) {
                int nsc_i = ctrl[c], ntc_i = ctrl[4 + c];
                double trt = acc[10 + c];
                double sss = av[c], sst = av[4 + c], ssst = av[8 + c];
                double trs = (double)nsc_i;
                double info_s = sss / ((trs + EPS) * (trs + EPS));
                double h_s = -log(info_s + EPS) / LOG2;
                double info_t = sst / ((trt + EPS) * (trt + EPS));
                double h_t = -log(info_t + EPS) / LOG2;
                double trm = trs + trt;
                double ssm = sss + 2.0 * ssst + sst;
                double info_m = ssm / ((trm + EPS) * (trm + EPS));
                double h_m = -log(info_m + EPS) / LOG2;
                double pc = h_m - 0.5 * (h_s + h_t);
                if (nsc_i >= 2 && ntc_i >= 2) { creda_sum += pc; n_valid += 1.0; }
            }
            double creda = (n_valid > 0.0) ? creda_sum / n_valid : 0.0;
            out[0] = (float)(loss_cls + 1.0 * creda + 0.1 * loss_ent);
        }
    }
#undef STAGE
#undef COMPUTE_HALF
}

extern "C" void kernel_launch(void* const* d_in, const int* in_sizes, int n_in,
                              void* d_out, int out_size, void* d_ws, size_t ws_size,
                              hipStream_t stream) {
    const float* FS = (const float*)d_in[0];
    const float* LS = (const float*)d_in[1];
    const float* FT = (const float*)d_in[2];
    const float* LT = (const float*)d_in[3];
    const int* LAB = (const int*)d_in[4];

    char* ws = (char*)d_ws;
    unsigned char* fs = (unsigned char*)(ws);                 // 4 MB
    unsigned char* ft = (unsigned char*)(ws + 4194304);       // 4 MB
    char* p = ws + 8388608;
    float* nS  = (float*)(p);
    float* wS  = (float*)(p + 16384);
    int*   cS  = (int*)  (p + 32768);
    float* nT  = (float*)(p + 49152);
    float* wT  = (float*)(p + 65536);
    int*   cT  = (int*)  (p + 81920);
    int*   ctrl = (int*)  (p + 98304);        // 28 ints
    float* acc  = (float*)(p + 98304 + 128);  // 26 floats
    int4*  wl   = (int4*) (p + 98304 + 512);  // NWORK_MAX x 16 B
    int*   dstS = (int*)  (p + 98304 + 512 + NWORK_MAX * 16);
    int*   dstT = dstS + NS_ROWS;

    rank_prep<<<2, 1024, 0, stream>>>(LAB, LS, LT, ctrl, acc, dstS, dstT);
    scatter_aux<<<2049, 256, 0, stream>>>(FS, FT, LAB, LT, dstS, dstT, fs, ft,
                                          nS, wS, cS, nT, wT, cT, ctrl, wl, acc);
    gemm_reduce<<<NWORK_MAX, 256, 0, stream>>>(fs, ft, nS, wS, cS, nT, wT, cT,
                                               ctrl, wl, acc, (float*)d_out);
}

// Round 13
// 62.011 us; speedup vs baseline: 1.1224x; 1.0935x over previous
//
#include <hip/hip_runtime.h>
#include <cstdint>
#include <cstddef>

#define NS_ROWS 4096
#define NT_ROWS 4096
#define DIM 1024
#define NC 4
#define NWORK_MAX 2432
#define ACC_N 26

typedef __attribute__((ext_vector_type(4))) float f32x4;
typedef long long i64;

#define GLOBAL_AS __attribute__((address_space(1)))
#define LDS_AS __attribute__((address_space(3)))

// ---------------- ws layout ----------------
// fs (fp8, class-permuted source rows) @ 0        4,194,304 B
// ft (fp8, class-permuted target rows) @ 4194304  4,194,304 B
// p = ws + 8388608:
//   nS@0 wS@16K cS@32K nT@48K wT@64K cT@80K  (16 KB each)
//   ctrl@96K (28 ints)  acc@96K+128 (26 f)  wl@96K+512 (NWORK_MAX int4)
//   dstS@after wl  dstT@+16K
// ctrl: [0..3]cntS [4..7]cntT [16..19]baseS [20..23]baseT [24]nwork
// acc: [0]ce [1]ent [10..13]tr_t [14..17]ss_s [18..21]ss_t [22..25]ss_st

__device__ __forceinline__ int argmax4(float4 l) {
    int am = 0; float bm = l.x;
    if (l.y > bm) { bm = l.y; am = 1; }
    if (l.z > bm) { bm = l.z; am = 2; }
    if (l.w > bm) { bm = l.w; am = 3; }
    return am;
}

// Fused: deterministic counting-sort rank (wave-scan) + per-class counts/bases
// + per-row logits losses. block 0 = source, block 1 = target.
__global__ __launch_bounds__(1024)
void rank_prep(const int* __restrict__ labels, const float* __restrict__ LS,
               const float* __restrict__ LT,
               int* __restrict__ ctrl, float* __restrict__ acc,
               int* __restrict__ dstS, int* __restrict__ dstT) {
    __shared__ unsigned long long wtot[16];
    __shared__ float wred[16];
    __shared__ float cls4[NC];
    int t = threadIdx.x;
    int wid = t >> 6, lane = t & 63;
    bool isS = (blockIdx.x == 0);
    int* dst = isS ? dstS : dstT;
    const float EPSF = 1e-8f;
    const float INV_LOG2 = 1.44269504088896340736f;

    if (t < NC) cls4[t] = 0.f;

    int c4[4];
    float localScalar = 0.f;
    float localW2[NC] = {0.f, 0.f, 0.f, 0.f};
    if (isS) {
        int4 lab4 = ((const int4*)labels)[t];
        c4[0] = lab4.x; c4[1] = lab4.y; c4[2] = lab4.z; c4[3] = lab4.w;
#pragma unroll
        for (int i = 0; i < 4; ++i) {
            float4 l = ((const float4*)LS)[t * 4 + i];
            float m = fmaxf(fmaxf(l.x, l.y), fmaxf(l.z, l.w));
            float e = expf(l.x - m) + expf(l.y - m) + expf(l.z - m) + expf(l.w - m);
            float lse = m + logf(e);
            int lab = c4[i];
            float ll = (lab == 0) ? l.x : (lab == 1) ? l.y : (lab == 2) ? l.z : l.w;
            localScalar += lse - ll;
        }
    } else {
#pragma unroll
        for (int i = 0; i < 4; ++i) {
            float4 l = ((const float4*)LT)[t * 4 + i];
            int am = argmax4(l);
            c4[i] = am;
            float m = fmaxf(fmaxf(l.x, l.y), fmaxf(l.z, l.w));
            float p0 = expf(l.x - m), p1 = expf(l.y - m),
                  p2 = expf(l.z - m), p3 = expf(l.w - m);
            float s = p0 + p1 + p2 + p3;
            p0 /= s; p1 /= s; p2 /= s; p3 /= s;
            localScalar += p0 * logf(p0 + EPSF) + p1 * logf(p1 + EPSF) +
                           p2 * logf(p2 + EPSF) + p3 * logf(p3 + EPSF);
            float sumsq = p0 * p0 + p1 * p1 + p2 * p2 + p3 * p3;
            float h2 = -logf(sumsq + EPSF) * INV_LOG2;
            float w = 1.0f - h2 / (2.0f + EPSF);
            localW2[am] += w * w;
        }
    }

    unsigned long long packed = 0ULL;
#pragma unroll
    for (int i = 0; i < 4; ++i) packed += 1ULL << (c4[i] * 16);
    unsigned long long v = packed;
#pragma unroll
    for (int off = 1; off < 64; off <<= 1) {
        unsigned long long n = __shfl_up(v, off);
        if (lane >= off) v += n;
    }
    if (lane == 63) wtot[wid] = v;
    __syncthreads();
    if (t < 16) {
        unsigned long long x = wtot[t];
#pragma unroll
        for (int off = 1; off < 16; off <<= 1) {
            unsigned long long n = __shfl_up(x, off);
            if (lane >= off) x += n;
        }
        wtot[t] = x;
    }
    __syncthreads();
    unsigned long long incl = v + (wid > 0 ? wtot[wid - 1] : 0ULL);
    unsigned long long tot = wtot[15];
    unsigned long long ex = incl - packed;

    int baseC[NC]; int b = 0;
#pragma unroll
    for (int c = 0; c < NC; ++c) {
        baseC[c] = b;
        b += (int)((tot >> (c * 16)) & 0xFFFFULL);
    }
    if (t == 0) {
#pragma unroll
        for (int c = 0; c < NC; ++c) {
            ctrl[(isS ? 0 : 4) + c] = (int)((tot >> (c * 16)) & 0xFFFFULL);
            ctrl[(isS ? 16 : 20) + c] = baseC[c];
        }
    }
    int pref[NC];
#pragma unroll
    for (int c = 0; c < NC; ++c)
        pref[c] = (int)((ex >> (c * 16)) & 0xFFFFULL) + baseC[c];
#pragma unroll
    for (int i = 0; i < 4; ++i) {
        int c = c4[i];
        dst[t * 4 + i] = pref[c]++;
    }

    for (int off = 32; off; off >>= 1) localScalar += __shfl_xor(localScalar, off);
    if (lane == 0) wred[wid] = localScalar;
    if (!isS) {
#pragma unroll
        for (int c = 0; c < NC; ++c) {
            float x = localW2[c];
            for (int off = 32; off; off >>= 1) x += __shfl_xor(x, off);
            if (lane == 0 && x != 0.f) atomicAdd(&cls4[c], x);   // LDS atomic
        }
    }
    __syncthreads();
    if (t == 0) {
        float s = 0.f;
        for (int i = 0; i < 16; ++i) s += wred[i];
        acc[isS ? 0 : 1] = s;
    }
    if (!isS && t < NC) acc[10 + t] = cls4[t];
}

// fp8-convert + row norms of the QUANTIZED rows, scattered to class-contiguous
// buffers (wave per row). Block 2048 instead builds the worklist + zeroes the
// gemm accumulator slots (fused aux).
__global__ void scatter_aux(const float* __restrict__ FS, const float* __restrict__ FT,
                            const int* __restrict__ labels, const float* __restrict__ LT,
                            const int* __restrict__ dstS, const int* __restrict__ dstT,
                            unsigned char* __restrict__ fs, unsigned char* __restrict__ ft,
                            float* __restrict__ nS, float* __restrict__ wS, int* __restrict__ cS,
                            float* __restrict__ nT, float* __restrict__ wT, int* __restrict__ cT,
                            int* __restrict__ ctrl, int4* __restrict__ wl,
                            float* __restrict__ acc) {
    if (blockIdx.x == 2048) {   // ---- aux branch ----
        int t = threadIdx.x;
        if (t >= 12 && t < 24) acc[14 + (t - 12)] = 0.f;
        int Ts[NC], Tt[NC];
#pragma unroll
        for (int c = 0; c < NC; ++c) {
            Ts[c] = (ctrl[c] + 127) >> 7;
            Tt[c] = (ctrl[4 + c] + 127) >> 7;
        }
        int segSize[12];
#pragma unroll
        for (int c = 0; c < NC; ++c) {
            segSize[c * 3 + 0] = Ts[c] * (Ts[c] + 1) / 2;
            segSize[c * 3 + 1] = Tt[c] * (Tt[c] + 1) / 2;
            segSize[c * 3 + 2] = Ts[c] * Tt[c];
        }
        if (t == 31) {
            int n = 0;
            for (int s = 0; s < 12; ++s) n += segSize[s];
            ctrl[24] = n;
        }
        if (t >= 12) return;
        int base = 0;
        for (int s = 0; s < t; ++s) base += segSize[s];
        int c = t / 3, kind = t % 3;
        int4* w = wl + base;
        int n = 0;
        if (kind == 0) {
            for (int tj = 0; tj < Ts[c]; ++tj)
                for (int ti = 0; ti <= tj; ++ti) w[n++] = make_int4(0, c, ti, tj);
        } else if (kind == 1) {
            for (int tj = 0; tj < Tt[c]; ++tj)
                for (int ti = 0; ti <= tj; ++ti) w[n++] = make_int4(1, c, ti, tj);
        } else {
            for (int ti = 0; ti < Ts[c]; ++ti)
                for (int tj = 0; tj < Tt[c]; ++tj) w[n++] = make_int4(2, c, ti, tj);
        }
        return;
    }

    int row = blockIdx.x * 4 + (threadIdx.x >> 6);
    int lane = threadIdx.x & 63;
    bool isS = row < NS_ROWS;
    int r = isS ? row : row - NS_ROWS;
    int dst = isS ? dstS[r] : dstT[r];

    const float* src = (isS ? FS : FT) + (size_t)r * DIM;
    float4 v0 = ((const float4*)src)[lane * 4 + 0];
    float4 v1 = ((const float4*)src)[lane * 4 + 1];
    float4 v2 = ((const float4*)src)[lane * 4 + 2];
    float4 v3 = ((const float4*)src)[lane * 4 + 3];
    int w0 = 0, w1 = 0, w2 = 0, w3 = 0;
    w0 = __builtin_amdgcn_cvt_pk_fp8_f32(v0.x, v0.y, w0, false);
    w0 = __builtin_amdgcn_cvt_pk_fp8_f32(v0.z, v0.w, w0, true);
    w1 = __builtin_amdgcn_cvt_pk_fp8_f32(v1.x, v1.y, w1, false);
    w1 = __builtin_amdgcn_cvt_pk_fp8_f32(v1.z, v1.w, w1, true);
    w2 = __builtin_amdgcn_cvt_pk_fp8_f32(v2.x, v2.y, w2, false);
    w2 = __builtin_amdgcn_cvt_pk_fp8_f32(v2.z, v2.w, w2, true);
    w3 = __builtin_amdgcn_cvt_pk_fp8_f32(v3.x, v3.y, w3, false);
    w3 = __builtin_amdgcn_cvt_pk_fp8_f32(v3.z, v3.w, w3, true);

    float ssum = 0.f;
#define ACCQ(wv)                                                       \
    do {                                                               \
        float q0 = __builtin_amdgcn_cvt_f32_fp8((wv), 0);              \
        float q1 = __builtin_amdgcn_cvt_f32_fp8((wv), 1);              \
        float q2 = __builtin_amdgcn_cvt_f32_fp8((wv), 2);              \
        float q3 = __builtin_amdgcn_cvt_f32_fp8((wv), 3);              \
        ssum += q0 * q0 + q1 * q1 + q2 * q2 + q3 * q3;                 \
    } while (0)
    ACCQ(w0); ACCQ(w1); ACCQ(w2); ACCQ(w3);
#undef ACCQ

    unsigned char* fdst = (isS ? fs : ft) + (size_t)dst * DIM;
    *(uint4*)(fdst + lane * 16) = make_uint4((unsigned)w0, (unsigned)w1,
                                             (unsigned)w2, (unsigned)w3);

    for (int off = 32; off; off >>= 1) ssum += __shfl_xor(ssum, off);

    if (lane == 0) {
        if (isS) {
            nS[dst] = ssum; wS[dst] = 1.0f; cS[dst] = labels[r];
        } else {
            float4 l = ((const float4*)LT)[r];
            int am = argmax4(l);
            float m = fmaxf(fmaxf(l.x, l.y), fmaxf(l.z, l.w));
            float p0 = expf(l.x - m), p1 = expf(l.y - m),
                  p2 = expf(l.z - m), p3 = expf(l.w - m);
            float s = p0 + p1 + p2 + p3;
            float sumsq = (p0 * p0 + p1 * p1 + p2 * p2 + p3 * p3) / (s * s);
            const float INV_LOG2 = 1.44269504088896340736f;
            float h2 = -logf(sumsq + 1e-8f) * INV_LOG2;
            float w = 1.0f - h2 / (2.0f + 1e-8f);
            nT[dst] = ssum; wT[dst] = w * w; cT[dst] = am;
        }
    }
}

// Fused fp8 GEMM (A@B^T) + RBF + weighted reduction, class-partitioned tiles.
// EXACT R10 tail restored: plain atomicAdd, const ctrl, NO __threadfence, NO
// done-counter — the fused-finalize fence (device-scope seq_cst -> buffer_wbl2
// L2 writeback per block) was the R11/R12 +11us regression. Finalize is a
// separate 1-block kernel again (kernel boundary provides the ordering).
// 128x128 tile, 4 waves, BK=64, both-sides 16B-chunk XOR swizzle, 2-phase.
__global__ __launch_bounds__(256, 4)
void gemm_reduce(const unsigned char* __restrict__ fs, const unsigned char* __restrict__ ft,
                 const float* __restrict__ nS, const float* __restrict__ wS, const int* __restrict__ cS,
                 const float* __restrict__ nT, const float* __restrict__ wT, const int* __restrict__ cT,
                 const int* __restrict__ ctrl, const int4* __restrict__ wl,
                 float* __restrict__ acc) {
    __shared__ unsigned char As[2][128 * 64];
    __shared__ unsigned char Bs[2][128 * 64];
    __shared__ float sred;

    int nwork = ctrl[24];
    int chunk = (nwork + 7) >> 3;
    int sub = blockIdx.x >> 3, xcd = blockIdx.x & 7;
    if (sub >= chunk) return;
    int widx = xcd * chunk + sub;
    if (widx >= nwork) return;
    int4 it = wl[widx];
    int kind = it.x, cls = it.y, ti = it.z, tj = it.w;

    const unsigned char *A, *B;
    const float *nA, *nB, *wA, *wB;
    const int *cA, *cB;
    int baseA, baseB;
    if (kind == 0)      { A = fs; B = fs; nA = nS; nB = nS; wA = wS; wB = wS; cA = cS; cB = cS;
                          baseA = ctrl[16 + cls]; baseB = baseA; }
    else if (kind == 1) { A = ft; B = ft; nA = nT; nB = nT; wA = wT; wB = wT; cA = cT; cB = cT;
                          baseA = ctrl[20 + cls]; baseB = baseA; }
    else                { A = fs; B = ft; nA = nS; nB = nT; wA = wS; cA = cS; cB = cT;
                          wB = wS;   // ss_st is mask-only on both sides
                          baseA = ctrl[16 + cls]; baseB = ctrl[20 + cls]; }
    float* outp = acc + 14 + kind * 4 + cls;
    float factor = (kind != 2 && ti != tj) ? 2.0f : 1.0f;

    int tid = threadIdx.x;
    int lane = tid & 63;
    int wid = tid >> 6;
    int wr = wid >> 1, wc = wid & 1;

    int rowA0 = baseA + ti * 128;
    int rowB0 = baseB + tj * 128;

    int srow = tid >> 2;                              // 0..63
    int sb = (((tid & 3) ^ ((tid >> 3) & 3))) * 16;   // inverse-swizzled src chunk

    const unsigned char* pa0 = A + (size_t)min(rowA0 + srow,      4095) * DIM + sb;
    const unsigned char* pa1 = A + (size_t)min(rowA0 + srow + 64, 4095) * DIM + sb;
    const unsigned char* pb0 = B + (size_t)min(rowB0 + srow,      4095) * DIM + sb;
    const unsigned char* pb1 = B + (size_t)min(rowB0 + srow + 64, 4095) * DIM + sb;

    f32x4 accf[4][4];
#pragma unroll
    for (int m = 0; m < 4; ++m)
#pragma unroll
        for (int n = 0; n < 4; ++n) accf[m][n] = (f32x4)(0.f);

    int lr = lane & 15;
    int lk = (lane >> 4) * 8;
    int sw = (lr >> 1) & 3;             // per-lane swizzle key

#define STAGE(buf, kt)                                                            \
    do {                                                                          \
        int k0_ = (kt) * 64;                                                      \
        __builtin_amdgcn_global_load_lds((const GLOBAL_AS void*)(pa0 + k0_),      \
            (LDS_AS void*)(As[buf] + tid * 16), 16, 0, 0);                        \
        __builtin_amdgcn_global_load_lds((const GLOBAL_AS void*)(pa1 + k0_),      \
            (LDS_AS void*)(As[buf] + 4096 + tid * 16), 16, 0, 0);                 \
        __builtin_amdgcn_global_load_lds((const GLOBAL_AS void*)(pb0 + k0_),      \
            (LDS_AS void*)(Bs[buf] + tid * 16), 16, 0, 0);                        \
        __builtin_amdgcn_global_load_lds((const GLOBAL_AS void*)(pb1 + k0_),      \
            (LDS_AS void*)(Bs[buf] + 4096 + tid * 16), 16, 0, 0);                 \
    } while (0)

#define COMPUTE_HALF(buf, kk)                                                     \
    do {                                                                          \
        int b_ = (kk) + lk;                                                       \
        int bs_ = ((((b_) >> 4) ^ sw) << 4) | ((b_) & 15);                        \
        i64 af[4], bfr[4];                                                        \
        _Pragma("unroll")                                                         \
        for (int f = 0; f < 4; ++f)                                               \
            af[f] = *(const i64*)(As[buf] + (wr * 64 + f * 16 + lr) * 64 + bs_);  \
        _Pragma("unroll")                                                         \
        for (int f = 0; f < 4; ++f)                                               \
            bfr[f] = *(const i64*)(Bs[buf] + (wc * 64 + f * 16 + lr) * 64 + bs_); \
        _Pragma("unroll")                                                         \
        for (int m = 0; m < 4; ++m)                                               \
            _Pragma("unroll")                                                     \
            for (int n = 0; n < 4; ++n)                                           \
                accf[m][n] = __builtin_amdgcn_mfma_f32_16x16x32_fp8_fp8(          \
                    af[m], bfr[n], accf[m][n], 0, 0, 0);                          \
    } while (0)

    STAGE(0, 0);
    asm volatile("s_waitcnt vmcnt(0)");
    __syncthreads();

    int cur = 0;
    for (int kt = 0; kt < DIM / 64 - 1; ++kt) {
        STAGE(cur ^ 1, kt + 1);     // next tile's loads fly during compute
        COMPUTE_HALF(cur, 0);
        COMPUTE_HALF(cur, 32);
        __syncthreads();            // drains vmcnt(0)+lgkmcnt(0); next buf ready
        cur ^= 1;
    }
    COMPUTE_HALF(cur, 0);
    COMPUTE_HALF(cur, 32);

    // ---- fused epilogue: d2 -> K^2 -> weighted accumulate ----
    int rowBase = rowA0 + wr * 64;
    int colBase = rowB0 + wc * 64;

    float cn[4], cw[4];
#pragma unroll
    for (int f = 0; f < 4; ++f) {
        int gj = colBase + f * 16 + lr;
        int gjc = min(gj, 4095);
        cn[f] = nB[gjc];
        cw[f] = (gj < 4096 && cB[gjc] == cls) ? wB[gjc] : 0.0f;
    }

    const float NEGF = (-2.0f / (2.0f * 32.0f * 32.0f + 1e-8f)) * 1.44269504088896340736f;
    float lacc = 0.f;

#pragma unroll
    for (int m = 0; m < 4; ++m) {
#pragma unroll
        for (int j = 0; j < 4; ++j) {
            int gi = rowBase + m * 16 + (lane >> 4) * 4 + j;
            int gic = min(gi, 4095);
            float rn = nA[gic];
            float rw = (gi < 4096 && cA[gic] == cls) ? wA[gic] : 0.0f;
#pragma unroll
            for (int n = 0; n < 4; ++n) {
                float dot = accf[m][n][j];
                float d2 = rn + cn[n] - 2.0f * dot;
                d2 = fmaxf(d2, 0.0f);
                float k2 = exp2f(d2 * NEGF);        // = K^2
                lacc += k2 * rw * cw[n];
            }
        }
    }

    if (tid == 0) sred = 0.f;
    __syncthreads();
    for (int off = 32; off; off >>= 1) lacc += __shfl_xor(lacc, off);
    if (lane == 0) atomicAdd(&sred, lacc);
    __syncthreads();
    if (tid == 0) atomicAdd(outp, factor * sred);
#undef STAGE
#undef COMPUTE_HALF
}

__global__ void finalize_kernel(const float* __restrict__ acc, const int* __restrict__ ctrl,
                                float* __restrict__ out) {
    if (threadIdx.x != 0 || blockIdx.x != 0) return;
    const double EPS = 1e-8;
    const double LOG2 = 0.6931471805599453;
    double loss_cls = (double)acc[0] / NS_ROWS;
    double loss_ent = -(double)acc[1] / NT_ROWS;
    double creda_sum = 0.0, n_valid = 0.0;
    for (int c = 0; c < NC; ++c) {
        int nsc_i = ctrl[c], ntc_i = ctrl[4 + c];
        double trt = acc[10 + c];
        double sss = acc[14 + c], sst = acc[18 + c], ssst = acc[22 + c];
        double trs = (double)nsc_i;
        double info_s = sss / ((trs + EPS) * (trs + EPS));
        double h_s = -log(info_s + EPS) / LOG2;
        double info_t = sst / ((trt + EPS) * (trt + EPS));
        double h_t = -log(info_t + EPS) / LOG2;
        double trm = trs + trt;
        double ssm = sss + 2.0 * ssst + sst;
        double info_m = ssm / ((trm + EPS) * (trm + EPS));
        double h_m = -log(info_m + EPS) / LOG2;
        double pc = h_m - 0.5 * (h_s + h_t);
        if (nsc_i >= 2 && ntc_i >= 2) { creda_sum += pc; n_valid += 1.0; }
    }
    double creda = (n_valid > 0.0) ? creda_sum / n_valid : 0.0;
    out[0] = (float)(loss_cls + 1.0 * creda + 0.1 * loss_ent);
}

extern "C" void kernel_launch(void* const* d_in, const int* in_sizes, int n_in,
                              void* d_out, int out_size, void* d_ws, size_t ws_size,
                              hipStream_t stream) {
    const float* FS = (const float*)d_in[0];
    const float* LS = (const float*)d_in[1];
    const float* FT = (const float*)d_in[2];
    const float* LT = (const float*)d_in[3];
    const int* LAB = (const int*)d_in[4];

    char* ws = (char*)d_ws;
    unsigned char* fs = (unsigned char*)(ws);                 // 4 MB
    unsigned char* ft = (unsigned char*)(ws + 4194304);       // 4 MB
    char* p = ws + 8388608;
    float* nS  = (float*)(p);
    float* wS  = (float*)(p + 16384);
    int*   cS  = (int*)  (p + 32768);
    float* nT  = (float*)(p + 49152);
    float* wT  = (float*)(p + 65536);
    int*   cT  = (int*)  (p + 81920);
    int*   ctrl = (int*)  (p + 98304);        // 28 ints
    float* acc  = (float*)(p + 98304 + 128);  // 26 floats
    int4*  wl   = (int4*) (p + 98304 + 512);  // NWORK_MAX x 16 B
    int*   dstS = (int*)  (p + 98304 + 512 + NWORK_MAX * 16);
    int*   dstT = dstS + NS_ROWS;

    rank_prep<<<2, 1024, 0, stream>>>(LAB, LS, LT, ctrl, acc, dstS, dstT);
    scatter_aux<<<2049, 256, 0, stream>>>(FS, FT, LAB, LT, dstS, dstT, fs, ft,
                                          nS, wS, cS, nT, wT, cT, ctrl, wl, acc);
    gemm_reduce<<<NWORK_MAX, 256, 0, stream>>>(fs, ft, nS, wS, cS, nT, wT, cT,
                                               ctrl, wl, acc);
    finalize_kernel<<<1, 1, 0, stream>>>(acc, ctrl, (float*)d_out);
}